// Round 4
// baseline (1435.979 us; speedup 1.0000x reference)
//
#include <hip/hip_runtime.h>
#include <cstdint>
#include <cstddef>

#define NEG_SLOPE 0.2f

static __device__ __forceinline__ float lrelu(float v) { return v > 0.f ? v : NEG_SLOPE * v; }

// ---------------- CSR build ----------------

__global__ __launch_bounds__(256) void count_deg_k(const int* __restrict__ dst, int E, int N,
                                                   int* __restrict__ cnt) {
    int i = blockIdx.x * 256 + threadIdx.x;
    if (i < E) {
        int d = dst[i];
        if ((unsigned)d < (unsigned)N) atomicAdd(&cnt[d], 1);
    }
}

// exclusive scan of (cnt[i] + 1)  [+1 = self loop], 1024 elements per block
__global__ __launch_bounds__(256) void scan1_k(const int* __restrict__ cnt, int N,
                                               int* __restrict__ rowptr, int* __restrict__ bsum) {
    __shared__ int tl[256];
    int base = blockIdx.x * 1024 + threadIdx.x * 4;
    int v[4];
    int run = 0;
    for (int j = 0; j < 4; ++j) {
        int idx = base + j;
        int x = (idx < N) ? (cnt[idx] + 1) : 0;
        v[j] = run;
        run += x;
    }
    tl[threadIdx.x] = run;
    __syncthreads();
    for (int off = 1; off < 256; off <<= 1) {
        int t = (threadIdx.x >= off) ? tl[threadIdx.x - off] : 0;
        __syncthreads();
        tl[threadIdx.x] += t;
        __syncthreads();
    }
    int excl = (threadIdx.x == 0) ? 0 : tl[threadIdx.x - 1];
    for (int j = 0; j < 4; ++j) {
        int idx = base + j;
        if (idx < N) rowptr[idx] = excl + v[j];
    }
    if (threadIdx.x == 255) bsum[blockIdx.x] = tl[255];
}

__global__ __launch_bounds__(256) void scan2_k(int* __restrict__ bsum, int nb) {
    __shared__ int tl[256];
    int x = (threadIdx.x < nb) ? bsum[threadIdx.x] : 0;
    tl[threadIdx.x] = x;
    __syncthreads();
    for (int off = 1; off < 256; off <<= 1) {
        int t = (threadIdx.x >= off) ? tl[threadIdx.x - off] : 0;
        __syncthreads();
        tl[threadIdx.x] += t;
        __syncthreads();
    }
    int excl = (threadIdx.x == 0) ? 0 : tl[threadIdx.x - 1];
    if (threadIdx.x < nb) bsum[threadIdx.x] = excl;
}

__global__ __launch_bounds__(256) void scan3_k(int* __restrict__ rowptr, const int* __restrict__ bsum,
                                               int N, int total) {
    int i = blockIdx.x * 256 + threadIdx.x;
    if (i < N) rowptr[i] += bsum[i >> 10];
    if (i == N) rowptr[N] = total;
}

__global__ __launch_bounds__(256) void fill_k(const int* __restrict__ srcI, const int* __restrict__ dstI,
                                              int E, int N, const int* __restrict__ rowptr,
                                              int* __restrict__ cursor, int* __restrict__ colA,
                                              int* __restrict__ rowid) {
    int i = blockIdx.x * 256 + threadIdx.x;
    int M = E + N;
    if (i >= M) return;
    int s, d;
    if (i < E) {
        s = srcI[i];
        d = dstI[i];
    } else {
        s = i - E;  // self loop
        d = s;
    }
    if ((unsigned)d < (unsigned)N && (unsigned)s < (unsigned)N) {
        int p = rowptr[d] + atomicAdd(&cursor[d], 1);
        if (p < M) {
            colA[p] = s;
            rowid[p] = d;
        }
    }
}

// ---------------- h = X @ W (register-tiled), plus alpha_src / alpha_dst ----------------

__global__ __launch_bounds__(256) void gemm_alpha_k(const float* __restrict__ X, const float* __restrict__ W,
                                                    const float* __restrict__ a_s, const float* __restrict__ a_d,
                                                    float* __restrict__ Hout, float* __restrict__ asrc,
                                                    float* __restrict__ adst, int N) {
    __shared__ float Xt[32][68];   // [k][row], pad 68 keeps 16B alignment
    __shared__ float Wl[32][128];
    const int tid = threadIdx.x;
    const int rowBase = blockIdx.x * 64;
    const int tr = tid >> 5;   // 0..7
    const int tc = tid & 31;   // 0..31

    float acc[8][4];
#pragma unroll
    for (int i = 0; i < 8; ++i)
#pragma unroll
        for (int c = 0; c < 4; ++c) acc[i][c] = 0.f;

    for (int kc = 0; kc < 128; kc += 32) {
#pragma unroll
        for (int j = 0; j < 2; ++j) {
            int f = tid + 256 * j;       // 0..511
            int r = f >> 3;              // 0..63
            int kq = (f & 7) * 4;        // 0..28
            int gr = rowBase + r;
            float4 xv = make_float4(0.f, 0.f, 0.f, 0.f);
            if (gr < N) xv = *(const float4*)&X[(size_t)gr * 128 + kc + kq];
            Xt[kq + 0][r] = xv.x;
            Xt[kq + 1][r] = xv.y;
            Xt[kq + 2][r] = xv.z;
            Xt[kq + 3][r] = xv.w;
        }
#pragma unroll
        for (int j = 0; j < 4; ++j) {
            int f = tid + 256 * j;       // 0..1023
            int k = f >> 5;              // 0..31
            int c4 = (f & 31) * 4;       // 0..124
            *(float4*)&Wl[k][c4] = *(const float4*)&W[(size_t)(kc + k) * 128 + c4];
        }
        __syncthreads();

#pragma unroll
        for (int k = 0; k < 32; ++k) {
            float4 x0 = *(const float4*)&Xt[k][tr * 8];
            float4 x1 = *(const float4*)&Xt[k][tr * 8 + 4];
            float4 wv = *(const float4*)&Wl[k][tc * 4];
            const float xs[8] = {x0.x, x0.y, x0.z, x0.w, x1.x, x1.y, x1.z, x1.w};
#pragma unroll
            for (int i = 0; i < 8; ++i) {
                acc[i][0] = fmaf(xs[i], wv.x, acc[i][0]);
                acc[i][1] = fmaf(xs[i], wv.y, acc[i][1]);
                acc[i][2] = fmaf(xs[i], wv.z, acc[i][2]);
                acc[i][3] = fmaf(xs[i], wv.w, acc[i][3]);
            }
        }
        __syncthreads();
    }

    float4 asv = *(const float4*)&a_s[tc * 4];
    float4 adv = *(const float4*)&a_d[tc * 4];
    const int head = tc >> 3;

#pragma unroll
    for (int i = 0; i < 8; ++i) {
        float ps = acc[i][0] * asv.x + acc[i][1] * asv.y + acc[i][2] * asv.z + acc[i][3] * asv.w;
        float pd = acc[i][0] * adv.x + acc[i][1] * adv.y + acc[i][2] * adv.z + acc[i][3] * adv.w;
        ps += __shfl_down(ps, 4, 8);
        ps += __shfl_down(ps, 2, 8);
        ps += __shfl_down(ps, 1, 8);
        pd += __shfl_down(pd, 4, 8);
        pd += __shfl_down(pd, 2, 8);
        pd += __shfl_down(pd, 1, 8);
        int gr = rowBase + tr * 8 + i;
        if (gr < N) {
            *(float4*)&Hout[(size_t)gr * 128 + tc * 4] =
                make_float4(acc[i][0], acc[i][1], acc[i][2], acc[i][3]);
            if ((tid & 7) == 0) {
                asrc[gr * 4 + head] = ps;
                adst[gr * 4 + head] = pd;
            }
        }
    }
}

// ---------------- edge-parallel unnormalized weights + denominator atomics ----------------
// No max-subtraction: |logits| <= ~6 for this model scale, exp() is fp32-safe.
// rowid[] is non-decreasing, so adst/den accesses are near-broadcast within a wave.

__global__ __launch_bounds__(256) void wgt_k(const int* __restrict__ colA, const int* __restrict__ rowid,
                                             const float* __restrict__ asrc, const float* __restrict__ adst,
                                             float* __restrict__ wgtA, float* __restrict__ den, int M) {
    int p = blockIdx.x * 256 + threadIdx.x;
    if (p >= M) return;
    int s = colA[p];
    int d = rowid[p];
    float4 as = *(const float4*)&asrc[s * 4];
    float4 ad = *(const float4*)&adst[d * 4];
    float4 w;
    w.x = __expf(lrelu(as.x + ad.x));
    w.y = __expf(lrelu(as.y + ad.y));
    w.z = __expf(lrelu(as.z + ad.z));
    w.w = __expf(lrelu(as.w + ad.w));
    *(float4*)&wgtA[(size_t)p * 4] = w;
    atomicAdd(&den[d * 4 + 0], w.x);
    atomicAdd(&den[d * 4 + 1], w.y);
    atomicAdd(&den[d * 4 + 2], w.z);
    atomicAdd(&den[d * 4 + 3], w.w);
}

// ---------------- aggregation: one wave per dst node, unroll x8, normalize at end ----------------

__global__ __launch_bounds__(256) void aggregate_k(const float* __restrict__ Hbuf,
                                                   const float* __restrict__ wgtA,
                                                   const float* __restrict__ den,
                                                   const int* __restrict__ rowptr,
                                                   const int* __restrict__ colA,
                                                   const float* __restrict__ bias,
                                                   float* __restrict__ out, int N) {
    int wave = (blockIdx.x * 256 + threadIdx.x) >> 6;
    int lane = threadIdx.x & 63;
    if (wave >= N) return;
    int n = wave;
    int c0 = lane * 2;
    int head = c0 >> 5;
    float acc0 = 0.f, acc1 = 0.f;
    int b = rowptr[n], e = rowptr[n + 1];
    int p = b;
    for (; p + 8 <= e; p += 8) {
        int s[8];
#pragma unroll
        for (int j = 0; j < 8; ++j) s[j] = colA[p + j];
        float w[8];
#pragma unroll
        for (int j = 0; j < 8; ++j) w[j] = wgtA[(size_t)(p + j) * 4 + head];
        float2 h[8];
#pragma unroll
        for (int j = 0; j < 8; ++j) h[j] = *(const float2*)&Hbuf[(size_t)s[j] * 128 + c0];
#pragma unroll
        for (int j = 0; j < 8; ++j) {
            acc0 = fmaf(w[j], h[j].x, acc0);
            acc1 = fmaf(w[j], h[j].y, acc1);
        }
    }
    for (; p + 2 <= e; p += 2) {
        int s0 = colA[p], s1 = colA[p + 1];
        float w0 = wgtA[(size_t)p * 4 + head];
        float w1 = wgtA[(size_t)(p + 1) * 4 + head];
        float2 h0 = *(const float2*)&Hbuf[(size_t)s0 * 128 + c0];
        float2 h1 = *(const float2*)&Hbuf[(size_t)s1 * 128 + c0];
        acc0 = fmaf(w0, h0.x, acc0);
        acc1 = fmaf(w0, h0.y, acc1);
        acc0 = fmaf(w1, h1.x, acc0);
        acc1 = fmaf(w1, h1.y, acc1);
    }
    for (; p < e; ++p) {
        int s = colA[p];
        float w = wgtA[(size_t)p * 4 + head];
        float2 hv = *(const float2*)&Hbuf[(size_t)s * 128 + c0];
        acc0 = fmaf(w, hv.x, acc0);
        acc1 = fmaf(w, hv.y, acc1);
    }
    float inv_dh = 1.f / den[n * 4 + head];
    float o0 = fmaxf(acc0 * inv_dh + bias[c0], 0.f);
    float o1 = fmaxf(acc1 * inv_dh + bias[c0 + 1], 0.f);
    *(float2*)&out[(size_t)n * 128 + c0] = make_float2(o0, o1);
}

// ---------------- launch ----------------

extern "C" void kernel_launch(void* const* d_in, const int* in_sizes, int n_in,
                              void* d_out, int out_size, void* d_ws, size_t ws_size,
                              hipStream_t stream) {
    const float* X   = (const float*)d_in[0];
    const int*   EI  = (const int*)d_in[1];
    const float* W1  = (const float*)d_in[2];
    const float* as1 = (const float*)d_in[3];
    const float* ad1 = (const float*)d_in[4];
    const float* b1  = (const float*)d_in[5];
    const float* W2  = (const float*)d_in[6];
    const float* as2 = (const float*)d_in[7];
    const float* ad2 = (const float*)d_in[8];
    const float* b2  = (const float*)d_in[9];

    const int N = in_sizes[0] / 128;
    const int E = in_sizes[1] / 2;
    const int M = E + N;
    const int* srcI = EI;
    const int* dstI = EI + E;

    char* w = (char*)d_ws;
    auto alloc = [&](size_t bytes) {
        char* p = w;
        w += (bytes + 255) & ~(size_t)255;
        return p;
    };
    float* Hbuf   = (float*)alloc((size_t)N * 128 * 4);
    float* wgtA   = (float*)alloc((size_t)M * 4 * 4);
    float* asrc   = (float*)alloc((size_t)N * 4 * 4);
    float* adst   = (float*)alloc((size_t)N * 4 * 4);
    float* den    = (float*)alloc((size_t)N * 4 * 4);
    int*   cnt    = (int*)alloc((size_t)N * 4);
    int*   cursor = (int*)alloc((size_t)N * 4);
    int*   rowptr = (int*)alloc((size_t)(N + 1) * 4);
    int*   colA   = (int*)alloc((size_t)M * 4);
    int*   rowid  = (int*)alloc((size_t)M * 4);
    int*   bsum   = (int*)alloc(1024 * 4);

    hipMemsetAsync(cnt, 0, (size_t)N * 4, stream);
    hipMemsetAsync(cursor, 0, (size_t)N * 4, stream);

    // CSR build (shared by both layers)
    count_deg_k<<<(E + 255) / 256, 256, 0, stream>>>(dstI, E, N, cnt);
    int nb1 = (N + 1023) / 1024;
    scan1_k<<<nb1, 256, 0, stream>>>(cnt, N, rowptr, bsum);
    scan2_k<<<1, 256, 0, stream>>>(bsum, nb1);
    scan3_k<<<(N + 1 + 255) / 256, 256, 0, stream>>>(rowptr, bsum, N, M);
    fill_k<<<(M + 255) / 256, 256, 0, stream>>>(srcI, dstI, E, N, rowptr, cursor, colA, rowid);

    float* out = (float*)d_out;

    // layer 1 (activation staged in d_out)
    gemm_alpha_k<<<(N + 63) / 64, 256, 0, stream>>>(X, W1, as1, ad1, Hbuf, asrc, adst, N);
    hipMemsetAsync(den, 0, (size_t)N * 4 * 4, stream);
    wgt_k<<<(M + 255) / 256, 256, 0, stream>>>(colA, rowid, asrc, adst, wgtA, den, M);
    aggregate_k<<<((size_t)N * 64 + 255) / 256, 256, 0, stream>>>(Hbuf, wgtA, den, rowptr, colA, b1, out, N);
    // layer 2
    gemm_alpha_k<<<(N + 63) / 64, 256, 0, stream>>>(out, W2, as2, ad2, Hbuf, asrc, adst, N);
    hipMemsetAsync(den, 0, (size_t)N * 4 * 4, stream);
    wgt_k<<<(M + 255) / 256, 256, 0, stream>>>(colA, rowid, asrc, adst, wgtA, den, M);
    aggregate_k<<<((size_t)N * 64 + 255) / 256, 256, 0, stream>>>(Hbuf, wgtA, den, rowptr, colA, b2, out, N);
}

// Round 5
// 642.617 us; speedup vs baseline: 2.2346x; 2.2346x over previous
//
#include <hip/hip_runtime.h>
#include <cstdint>
#include <cstddef>

#define NEG_SLOPE 0.2f

static __device__ __forceinline__ float lrelu(float v) { return v > 0.f ? v : NEG_SLOPE * v; }

// ---------------- CSR build ----------------

__global__ __launch_bounds__(256) void count_deg_k(const int* __restrict__ dst, int E, int N,
                                                   int* __restrict__ cnt) {
    int i = blockIdx.x * 256 + threadIdx.x;
    if (i < E) {
        int d = dst[i];
        if ((unsigned)d < (unsigned)N) atomicAdd(&cnt[d], 1);
    }
}

// exclusive scan of (cnt[i] + 1)  [+1 = self loop], 1024 elements per block
__global__ __launch_bounds__(256) void scan1_k(const int* __restrict__ cnt, int N,
                                               int* __restrict__ rowptr, int* __restrict__ bsum) {
    __shared__ int tl[256];
    int base = blockIdx.x * 1024 + threadIdx.x * 4;
    int v[4];
    int run = 0;
    for (int j = 0; j < 4; ++j) {
        int idx = base + j;
        int x = (idx < N) ? (cnt[idx] + 1) : 0;
        v[j] = run;
        run += x;
    }
    tl[threadIdx.x] = run;
    __syncthreads();
    for (int off = 1; off < 256; off <<= 1) {
        int t = (threadIdx.x >= off) ? tl[threadIdx.x - off] : 0;
        __syncthreads();
        tl[threadIdx.x] += t;
        __syncthreads();
    }
    int excl = (threadIdx.x == 0) ? 0 : tl[threadIdx.x - 1];
    for (int j = 0; j < 4; ++j) {
        int idx = base + j;
        if (idx < N) rowptr[idx] = excl + v[j];
    }
    if (threadIdx.x == 255) bsum[blockIdx.x] = tl[255];
}

__global__ __launch_bounds__(256) void scan2_k(int* __restrict__ bsum, int nb) {
    __shared__ int tl[256];
    int x = (threadIdx.x < nb) ? bsum[threadIdx.x] : 0;
    tl[threadIdx.x] = x;
    __syncthreads();
    for (int off = 1; off < 256; off <<= 1) {
        int t = (threadIdx.x >= off) ? tl[threadIdx.x - off] : 0;
        __syncthreads();
        tl[threadIdx.x] += t;
        __syncthreads();
    }
    int excl = (threadIdx.x == 0) ? 0 : tl[threadIdx.x - 1];
    if (threadIdx.x < nb) bsum[threadIdx.x] = excl;
}

__global__ __launch_bounds__(256) void scan3_k(int* __restrict__ rowptr, const int* __restrict__ bsum,
                                               int N, int total) {
    int i = blockIdx.x * 256 + threadIdx.x;
    if (i < N) rowptr[i] += bsum[i >> 10];
    if (i == N) rowptr[N] = total;
}

__global__ __launch_bounds__(256) void fill_k(const int* __restrict__ srcI, const int* __restrict__ dstI,
                                              int E, int N, const int* __restrict__ rowptr,
                                              int* __restrict__ cursor, int* __restrict__ colA,
                                              int* __restrict__ rowid) {
    int i = blockIdx.x * 256 + threadIdx.x;
    int M = E + N;
    if (i >= M) return;
    int s, d;
    if (i < E) {
        s = srcI[i];
        d = dstI[i];
    } else {
        s = i - E;  // self loop
        d = s;
    }
    if ((unsigned)d < (unsigned)N && (unsigned)s < (unsigned)N) {
        int p = rowptr[d] + atomicAdd(&cursor[d], 1);
        if (p < M) {
            colA[p] = s;
            rowid[p] = d;
        }
    }
}

// ---------------- h = X @ W (register-tiled), plus alpha_src / alpha_dst ----------------

__global__ __launch_bounds__(256) void gemm_alpha_k(const float* __restrict__ X, const float* __restrict__ W,
                                                    const float* __restrict__ a_s, const float* __restrict__ a_d,
                                                    float* __restrict__ Hout, float* __restrict__ asrc,
                                                    float* __restrict__ adst, int N) {
    __shared__ float Xt[32][68];   // [k][row], pad 68 keeps 16B alignment
    __shared__ float Wl[32][128];
    const int tid = threadIdx.x;
    const int rowBase = blockIdx.x * 64;
    const int tr = tid >> 5;   // 0..7
    const int tc = tid & 31;   // 0..31

    float acc[8][4];
#pragma unroll
    for (int i = 0; i < 8; ++i)
#pragma unroll
        for (int c = 0; c < 4; ++c) acc[i][c] = 0.f;

    for (int kc = 0; kc < 128; kc += 32) {
#pragma unroll
        for (int j = 0; j < 2; ++j) {
            int f = tid + 256 * j;       // 0..511
            int r = f >> 3;              // 0..63
            int kq = (f & 7) * 4;        // 0..28
            int gr = rowBase + r;
            float4 xv = make_float4(0.f, 0.f, 0.f, 0.f);
            if (gr < N) xv = *(const float4*)&X[(size_t)gr * 128 + kc + kq];
            Xt[kq + 0][r] = xv.x;
            Xt[kq + 1][r] = xv.y;
            Xt[kq + 2][r] = xv.z;
            Xt[kq + 3][r] = xv.w;
        }
#pragma unroll
        for (int j = 0; j < 4; ++j) {
            int f = tid + 256 * j;       // 0..1023
            int k = f >> 5;              // 0..31
            int c4 = (f & 31) * 4;       // 0..124
            *(float4*)&Wl[k][c4] = *(const float4*)&W[(size_t)(kc + k) * 128 + c4];
        }
        __syncthreads();

#pragma unroll
        for (int k = 0; k < 32; ++k) {
            float4 x0 = *(const float4*)&Xt[k][tr * 8];
            float4 x1 = *(const float4*)&Xt[k][tr * 8 + 4];
            float4 wv = *(const float4*)&Wl[k][tc * 4];
            const float xs[8] = {x0.x, x0.y, x0.z, x0.w, x1.x, x1.y, x1.z, x1.w};
#pragma unroll
            for (int i = 0; i < 8; ++i) {
                acc[i][0] = fmaf(xs[i], wv.x, acc[i][0]);
                acc[i][1] = fmaf(xs[i], wv.y, acc[i][1]);
                acc[i][2] = fmaf(xs[i], wv.z, acc[i][2]);
                acc[i][3] = fmaf(xs[i], wv.w, acc[i][3]);
            }
        }
        __syncthreads();
    }

    float4 asv = *(const float4*)&a_s[tc * 4];
    float4 adv = *(const float4*)&a_d[tc * 4];
    const int head = tc >> 3;

#pragma unroll
    for (int i = 0; i < 8; ++i) {
        float ps = acc[i][0] * asv.x + acc[i][1] * asv.y + acc[i][2] * asv.z + acc[i][3] * asv.w;
        float pd = acc[i][0] * adv.x + acc[i][1] * adv.y + acc[i][2] * adv.z + acc[i][3] * adv.w;
        ps += __shfl_down(ps, 4, 8);
        ps += __shfl_down(ps, 2, 8);
        ps += __shfl_down(ps, 1, 8);
        pd += __shfl_down(pd, 4, 8);
        pd += __shfl_down(pd, 2, 8);
        pd += __shfl_down(pd, 1, 8);
        int gr = rowBase + tr * 8 + i;
        if (gr < N) {
            *(float4*)&Hout[(size_t)gr * 128 + tc * 4] =
                make_float4(acc[i][0], acc[i][1], acc[i][2], acc[i][3]);
            if ((tid & 7) == 0) {
                asrc[gr * 4 + head] = ps;
                adst[gr * 4 + head] = pd;
            }
        }
    }
}

// ---------------- edge-parallel unnormalized weights (no atomics) ----------------
// No max-subtraction: logits are O(few) for this model scale, exp() is fp32-safe.
// asrc/adst are 1.6 MB each -> gathers hit L2. Denominator is summed in aggregate_k.

__global__ __launch_bounds__(256) void wgt_k(const int* __restrict__ colA, const int* __restrict__ rowid,
                                             const float* __restrict__ asrc, const float* __restrict__ adst,
                                             float* __restrict__ wgtA, int M) {
    int p = blockIdx.x * 256 + threadIdx.x;
    if (p >= M) return;
    int s = colA[p];
    int d = rowid[p];
    float4 as = *(const float4*)&asrc[s * 4];
    float4 ad = *(const float4*)&adst[d * 4];
    float4 w;
    w.x = __expf(lrelu(as.x + ad.x));
    w.y = __expf(lrelu(as.y + ad.y));
    w.z = __expf(lrelu(as.z + ad.z));
    w.w = __expf(lrelu(as.w + ad.w));
    *(float4*)&wgtA[(size_t)p * 4] = w;
}

// ---------------- aggregation: one wave per dst node, unroll x8 ----------------
// Denominator accumulated in-register alongside the weighted sum (free: every
// lane of a head reads every w of its row anyway).

__global__ __launch_bounds__(256) void aggregate_k(const float* __restrict__ Hbuf,
                                                   const float* __restrict__ wgtA,
                                                   const int* __restrict__ rowptr,
                                                   const int* __restrict__ colA,
                                                   const float* __restrict__ bias,
                                                   float* __restrict__ out, int N) {
    int wave = (blockIdx.x * 256 + threadIdx.x) >> 6;
    int lane = threadIdx.x & 63;
    if (wave >= N) return;
    int n = wave;
    int c0 = lane * 2;
    int head = c0 >> 5;
    float acc0 = 0.f, acc1 = 0.f, sw = 0.f;
    int b = rowptr[n], e = rowptr[n + 1];
    int p = b;
    for (; p + 8 <= e; p += 8) {
        int s[8];
#pragma unroll
        for (int j = 0; j < 8; ++j) s[j] = colA[p + j];
        float w[8];
#pragma unroll
        for (int j = 0; j < 8; ++j) w[j] = wgtA[(size_t)(p + j) * 4 + head];
        float2 h[8];
#pragma unroll
        for (int j = 0; j < 8; ++j) h[j] = *(const float2*)&Hbuf[(size_t)s[j] * 128 + c0];
#pragma unroll
        for (int j = 0; j < 8; ++j) {
            sw += w[j];
            acc0 = fmaf(w[j], h[j].x, acc0);
            acc1 = fmaf(w[j], h[j].y, acc1);
        }
    }
    for (; p + 2 <= e; p += 2) {
        int s0 = colA[p], s1 = colA[p + 1];
        float w0 = wgtA[(size_t)p * 4 + head];
        float w1 = wgtA[(size_t)(p + 1) * 4 + head];
        float2 h0 = *(const float2*)&Hbuf[(size_t)s0 * 128 + c0];
        float2 h1 = *(const float2*)&Hbuf[(size_t)s1 * 128 + c0];
        sw += w0 + w1;
        acc0 = fmaf(w0, h0.x, acc0);
        acc1 = fmaf(w0, h0.y, acc1);
        acc0 = fmaf(w1, h1.x, acc0);
        acc1 = fmaf(w1, h1.y, acc1);
    }
    for (; p < e; ++p) {
        int s = colA[p];
        float w = wgtA[(size_t)p * 4 + head];
        float2 hv = *(const float2*)&Hbuf[(size_t)s * 128 + c0];
        sw += w;
        acc0 = fmaf(w, hv.x, acc0);
        acc1 = fmaf(w, hv.y, acc1);
    }
    float inv_dh = 1.f / sw;
    float o0 = fmaxf(acc0 * inv_dh + bias[c0], 0.f);
    float o1 = fmaxf(acc1 * inv_dh + bias[c0 + 1], 0.f);
    *(float2*)&out[(size_t)n * 128 + c0] = make_float2(o0, o1);
}

// ---------------- launch ----------------

extern "C" void kernel_launch(void* const* d_in, const int* in_sizes, int n_in,
                              void* d_out, int out_size, void* d_ws, size_t ws_size,
                              hipStream_t stream) {
    const float* X   = (const float*)d_in[0];
    const int*   EI  = (const int*)d_in[1];
    const float* W1  = (const float*)d_in[2];
    const float* as1 = (const float*)d_in[3];
    const float* ad1 = (const float*)d_in[4];
    const float* b1  = (const float*)d_in[5];
    const float* W2  = (const float*)d_in[6];
    const float* as2 = (const float*)d_in[7];
    const float* ad2 = (const float*)d_in[8];
    const float* b2  = (const float*)d_in[9];

    const int N = in_sizes[0] / 128;
    const int E = in_sizes[1] / 2;
    const int M = E + N;
    const int* srcI = EI;
    const int* dstI = EI + E;

    char* w = (char*)d_ws;
    auto alloc = [&](size_t bytes) {
        char* p = w;
        w += (bytes + 255) & ~(size_t)255;
        return p;
    };
    float* Hbuf   = (float*)alloc((size_t)N * 128 * 4);
    float* wgtA   = (float*)alloc((size_t)M * 4 * 4);
    float* asrc   = (float*)alloc((size_t)N * 4 * 4);
    float* adst   = (float*)alloc((size_t)N * 4 * 4);
    int*   cnt    = (int*)alloc((size_t)N * 4);
    int*   cursor = (int*)alloc((size_t)N * 4);
    int*   rowptr = (int*)alloc((size_t)(N + 1) * 4);
    int*   colA   = (int*)alloc((size_t)M * 4);
    int*   rowid  = (int*)alloc((size_t)M * 4);
    int*   bsum   = (int*)alloc(1024 * 4);

    hipMemsetAsync(cnt, 0, (size_t)N * 4, stream);
    hipMemsetAsync(cursor, 0, (size_t)N * 4, stream);

    // CSR build (shared by both layers)
    count_deg_k<<<(E + 255) / 256, 256, 0, stream>>>(dstI, E, N, cnt);
    int nb1 = (N + 1023) / 1024;
    scan1_k<<<nb1, 256, 0, stream>>>(cnt, N, rowptr, bsum);
    scan2_k<<<1, 256, 0, stream>>>(bsum, nb1);
    scan3_k<<<(N + 1 + 255) / 256, 256, 0, stream>>>(rowptr, bsum, N, M);
    fill_k<<<(M + 255) / 256, 256, 0, stream>>>(srcI, dstI, E, N, rowptr, cursor, colA, rowid);

    float* out = (float*)d_out;

    // layer 1 (activation staged in d_out)
    gemm_alpha_k<<<(N + 63) / 64, 256, 0, stream>>>(X, W1, as1, ad1, Hbuf, asrc, adst, N);
    wgt_k<<<(M + 255) / 256, 256, 0, stream>>>(colA, rowid, asrc, adst, wgtA, M);
    aggregate_k<<<((size_t)N * 64 + 255) / 256, 256, 0, stream>>>(Hbuf, wgtA, rowptr, colA, b1, out, N);
    // layer 2
    gemm_alpha_k<<<(N + 63) / 64, 256, 0, stream>>>(out, W2, as2, ad2, Hbuf, asrc, adst, N);
    wgt_k<<<(M + 255) / 256, 256, 0, stream>>>(colA, rowid, asrc, adst, wgtA, M);
    aggregate_k<<<((size_t)N * 64 + 255) / 256, 256, 0, stream>>>(Hbuf, wgtA, rowptr, colA, b2, out, N);
}